// Round 4
// baseline (524.851 us; speedup 1.0000x reference)
//
#include <hip/hip_runtime.h>
#include <math.h>

// Problem constants: ALPHA=0.5, MAX_COEFF=10, SHARPNESS=5
// N_VARS=1e6, N_CLAUSES=4e6, N_EDGES=12e6

constexpr int   N_CLAUSES_C = 4000000;
constexpr int   BKT_SHIFT   = 10;                                        // 1024 clauses / bucket
constexpr int   BKT_CLS     = 1 << BKT_SHIFT;
constexpr int   NB_TOTAL    = (N_CLAUSES_C + BKT_CLS - 1) >> BKT_SHIFT;  // 3907
constexpr int   CAP         = 3520;   // max edges/bucket (mean 3072, sd 55; +8 sigma)
constexpr float EV_SCALE    = 4194303.0f;                                // 2^22 - 1
constexpr int   SC_BLOCKS   = 512;
constexpr int   SC_THREADS  = 1024;

typedef int   v4i __attribute__((ext_vector_type(4)));
typedef float v4f __attribute__((ext_vector_type(4)));

// Phase A: per-block histogram -> claim contiguous runs -> scatter packed payload.
// Single LDS array (15.6 KB): hist -> base -> running cursor.
__global__ __launch_bounds__(SC_THREADS) void
scatter_kernel(const float* __restrict__ vp,
               const int* __restrict__ lits,
               const int* __restrict__ cls,
               const float* __restrict__ ef,
               uint32_t* __restrict__ payload,   // [nbp][CAP]
               uint32_t* __restrict__ cursors,   // [NB_TOTAL], zeroed
               int n_edges, int b_lo, int b_hi) {
    __shared__ uint32_t hist[NB_TOTAL];
    const int nbp = b_hi - b_lo;

    for (int i = threadIdx.x; i < nbp; i += blockDim.x) hist[i] = 0;
    __syncthreads();

    int chunk = (n_edges + gridDim.x - 1) / gridDim.x;
    chunk = (chunk + 3) & ~3;
    const int c0 = blockIdx.x * chunk;
    const int c1 = min(n_edges, c0 + chunk);
    const bool vec_ok = ((n_edges & 3) == 0);

    // pass 1: count this block's edges per bucket (nontemporal stream reads)
    if (vec_ok) {
        for (int e = c0 + (int)threadIdx.x * 4; e < c1; e += blockDim.x * 4) {
            v4i c4 = __builtin_nontemporal_load((const v4i*)(cls + e));
            #pragma unroll
            for (int j = 0; j < 4; ++j) {
                int b = c4[j] >> BKT_SHIFT;
                if (b >= b_lo && b < b_hi) atomicAdd(&hist[b - b_lo], 1u);
            }
        }
    } else {
        for (int e = c0 + threadIdx.x; e < c1; e += blockDim.x) {
            int b = cls[e] >> BKT_SHIFT;
            if (b >= b_lo && b < b_hi) atomicAdd(&hist[b - b_lo], 1u);
        }
    }
    __syncthreads();

    // claim one contiguous global run per touched bucket; hist becomes the cursor
    for (int i = threadIdx.x; i < nbp; i += blockDim.x) {
        uint32_t h = hist[i];
        if (h) hist[i] = atomicAdd(&cursors[b_lo + i], h);
    }
    __syncthreads();

    // pass 2: scatter packed (ev_q22 << 10 | clause_local)
    if (vec_ok) {
        for (int e = c0 + (int)threadIdx.x * 4; e < c1; e += blockDim.x * 4) {
            v4i c4 = __builtin_nontemporal_load((const v4i*)(cls + e));
            v4i l4 = __builtin_nontemporal_load((const v4i*)(lits + e));
            v4f f4 = __builtin_nontemporal_load((const v4f*)(ef + e));
            #pragma unroll
            for (int j = 0; j < 4; ++j) {
                int c = c4[j];
                int b = c >> BKT_SHIFT;
                if (b < b_lo || b >= b_hi) continue;
                int i = b - b_lo;
                float f  = f4[j];
                float ev = fmaf(f, vp[l4[j]], (1.0f - f) * 0.5f);   // in [0,1]
                uint32_t evq = (uint32_t)(ev * EV_SCALE + 0.5f);
                uint32_t pos = atomicAdd(&hist[i], 1u);
                if (pos < (uint32_t)CAP)
                    payload[(size_t)i * CAP + pos] =
                        (evq << BKT_SHIFT) | (uint32_t)(c & (BKT_CLS - 1));
            }
        }
    } else {
        for (int e = c0 + threadIdx.x; e < c1; e += blockDim.x) {
            int c = cls[e];
            int b = c >> BKT_SHIFT;
            if (b < b_lo || b >= b_hi) continue;
            int i = b - b_lo;
            float f  = ef[e];
            float ev = fmaf(f, vp[lits[e]], (1.0f - f) * 0.5f);
            uint32_t evq = (uint32_t)(ev * EV_SCALE + 0.5f);
            uint32_t pos = atomicAdd(&hist[i], 1u);
            if (pos < (uint32_t)CAP)
                payload[(size_t)i * CAP + pos] =
                    (evq << BKT_SHIFT) | (uint32_t)(c & (BKT_CLS - 1));
        }
    }
}

// Phase B: one block per bucket. LDS float2 accumulators, then log epilogue.
__global__ void process_kernel(const uint32_t* __restrict__ payload,
                               const uint32_t* __restrict__ cursors,
                               const float* __restrict__ gstep,
                               const float* __restrict__ epsp,
                               double* __restrict__ acc,
                               int b_lo) {
    __shared__ float2 s[BKT_CLS];          // (nom, den) per clause: 8 KB
    __shared__ double wsum[8];
    const int b = b_lo + blockIdx.x;

    for (int j = threadIdx.x; j < BKT_CLS; j += blockDim.x) s[j] = make_float2(0.f, 0.f);
    __syncthreads();

    const float coeff = fminf(sqrtf(gstep[0]), 10.0f);
    const uint32_t cnt = min(cursors[b], (uint32_t)CAP);
    const uint32_t* pl = payload + (size_t)blockIdx.x * CAP;

    for (uint32_t k = threadIdx.x; k < cnt; k += blockDim.x) {
        uint32_t p = pl[k];
        int   cl = p & (BKT_CLS - 1);
        float ev = (float)(p >> BKT_SHIFT) * (1.0f / EV_SCALE);
        float w  = __expf(coeff * ev);
        atomicAdd(&s[cl].x, w * ev);
        atomicAdd(&s[cl].y, w);
    }
    __syncthreads();

    const float eps = epsp[0];
    double local = 0.0;
    const int gbase = b << BKT_SHIFT;
    for (int j = threadIdx.x; j < BKT_CLS; j += blockDim.x) {
        if (gbase + j < N_CLAUSES_C) {
            float2 nd = s[j];
            float cv = nd.y / fmaxf(nd.x, eps);     // den / max(nom, eps)
            float t  = cv - 1.0f;
            float t2 = t * t;
            float cv2 = 1.0f + t2 * t2 * t;          // 1 + (cv-1)^5
            local += (double)logf(fmaxf(cv2, eps));
        }
    }
    #pragma unroll
    for (int off = 32; off > 0; off >>= 1) local += __shfl_down(local, off, 64);
    int wid = threadIdx.x >> 6;
    if ((threadIdx.x & 63) == 0) wsum[wid] = local;
    __syncthreads();
    if (threadIdx.x == 0) {
        double t = 0.0;
        for (int w = 0; w < (int)blockDim.x / 64; ++w) t += wsum[w];
        unsafeAtomicAdd(acc, t);
    }
}

__global__ void finalize_kernel(const double* __restrict__ acc,
                                const int* __restrict__ ncp,
                                float* __restrict__ out) {
    if (threadIdx.x == 0 && blockIdx.x == 0)
        out[0] = (float)(acc[0] / (double)ncp[0]);
}

extern "C" void kernel_launch(void* const* d_in, const int* in_sizes, int n_in,
                              void* d_out, int out_size, void* d_ws, size_t ws_size,
                              hipStream_t stream) {
    const float* vp    = (const float*)d_in[0];
    const int*   gmap  = (const int*)d_in[1];
    const float* ef    = (const float*)d_in[2];
    const int*   ncp   = (const int*)d_in[3];
    const float* gstep = (const float*)d_in[4];
    const float* epsp  = (const float*)d_in[5];
    float*       out   = (float*)d_out;

    const int n_edges = in_sizes[1] / 2;
    const int* lits = gmap;
    const int* cls  = gmap + n_edges;

    // choose pass count so payload fits the workspace (P=1 needs ~55MB, P=2 ~28MB, ...)
    int P = 8;
    int nbp_max = (NB_TOTAL + 7) / 8;
    size_t cursors_off_w = (size_t)nbp_max * CAP;
    size_t acc_off_w = (cursors_off_w + NB_TOTAL + 1) & ~(size_t)1;
    const int cands[4] = {1, 2, 4, 8};
    for (int ci = 0; ci < 4; ++ci) {
        int cand = cands[ci];
        int nm = (NB_TOTAL + cand - 1) / cand;
        size_t pw = (size_t)nm * CAP;          // payload words
        size_t cw = pw + NB_TOTAL;             // cursors end (words)
        size_t aw = (cw + 1) & ~(size_t)1;     // 8B-aligned acc offset (words)
        size_t need = aw * 4 + 8;
        if (need <= ws_size) { P = cand; nbp_max = nm; cursors_off_w = pw; acc_off_w = aw; break; }
    }

    uint32_t* payload = (uint32_t*)d_ws;
    uint32_t* cursors = payload + cursors_off_w;
    double*   acc     = (double*)((uint32_t*)d_ws + acc_off_w);

    // zero cursors + accumulator every call (ws is poisoned, not re-zeroed)
    hipMemsetAsync(cursors, 0, (acc_off_w - cursors_off_w) * 4 + 8, stream);

    for (int p = 0; p < P; ++p) {
        int b_lo = p * nbp_max;
        int b_hi = min(NB_TOTAL, b_lo + nbp_max);
        if (b_lo >= b_hi) continue;
        scatter_kernel<<<SC_BLOCKS, SC_THREADS, 0, stream>>>(
            vp, lits, cls, ef, payload, cursors, n_edges, b_lo, b_hi);
        process_kernel<<<b_hi - b_lo, 256, 0, stream>>>(
            payload, cursors, gstep, epsp, acc, b_lo);
    }
    finalize_kernel<<<1, 64, 0, stream>>>(acc, ncp, out);
}

// Round 6
// 299.828 us; speedup vs baseline: 1.7505x; 1.7505x over previous
//
#include <hip/hip_runtime.h>
#include <math.h>

// Problem constants: ALPHA=0.5, MAX_COEFF=10, SHARPNESS=5
// N_VARS=1e6, N_CLAUSES=4e6, N_EDGES=12e6

constexpr int   N_CLAUSES_C = 4000000;
constexpr int   BKT_SHIFT   = 12;                                        // 4096 clauses / bucket
constexpr int   BKT_CLS     = 1 << BKT_SHIFT;
constexpr int   NB_TOTAL    = (N_CLAUSES_C + BKT_CLS - 1) >> BKT_SHIFT;  // 977
constexpr int   CAP         = 13056;   // mean 12282, sd ~111; +7 sigma, mult of 4
constexpr int   SC_THREADS  = 1024;
constexpr int   BATCH       = 8192;
constexpr int   SC_CHUNK    = 3 * BATCH;   // 24576

// ev encoding: top-20-bits-of-f32 with round-to-nearest.
// RELATIVE error <= 2^-13 at every magnitude (linear quant zeroed tiny ev and
// made cv = den/nom explode to inf). Exact for ev = k*2^-23 (jax uniform grid)
// and for 0; monotone; ev<=1.0 maps to <= 0x7F000 < 2^20.
__device__ __forceinline__ uint32_t ev_enc(float ev) {
    return (__float_as_uint(ev) + 0x400u) >> 11;
}
__device__ __forceinline__ float ev_dec(uint32_t q) {
    return __uint_as_float(q << 11);
}

// Phase A: block-level histogram -> claim runs -> batched LDS reorder ->
// coalesced payload write (bucket runs ~8 consecutive words, completed in L2).
__global__ __launch_bounds__(SC_THREADS) void
scatter_kernel(const float* __restrict__ vp,
               const int* __restrict__ lits,
               const int* __restrict__ cls,
               const float* __restrict__ ef,
               uint32_t* __restrict__ payload,   // [nbp][CAP]
               uint32_t* __restrict__ cursors,   // [NB_TOTAL], zeroed
               int n_edges, int b_lo, int b_hi) {
    __shared__ uint32_t curB[NB_TOTAL];   // hist -> claimed base + running offset
    __shared__ uint32_t bh[NB_TOTAL];     // per-batch histogram
    __shared__ uint32_t bOff[NB_TOTAL];   // per-batch exclusive scan
    __shared__ uint32_t buf[BATCH];       // staged packed entries (32 KB)
    __shared__ uint16_t bufB[BATCH];      // staged bucket ids (16 KB)
    __shared__ uint32_t wsums[16];
    __shared__ uint32_t totalS;

    const int tid  = threadIdx.x;
    const int lane = tid & 63;
    const int wv   = tid >> 6;
    const int nbp  = b_hi - b_lo;
    const int c0   = blockIdx.x * SC_CHUNK;
    const int c1   = min(n_edges, c0 + SC_CHUNK);

    for (int i = tid; i < nbp; i += SC_THREADS) curB[i] = 0;
    __syncthreads();

    // pass 1: block histogram over its chunk
    for (int e = c0 + tid; e < c1; e += SC_THREADS) {
        int b = __builtin_nontemporal_load(cls + e) >> BKT_SHIFT;
        if (b >= b_lo && b < b_hi) atomicAdd(&curB[b - b_lo], 1u);
    }
    __syncthreads();

    // claim one contiguous global run per touched bucket
    for (int i = tid; i < nbp; i += SC_THREADS) {
        uint32_t h = curB[i];
        curB[i] = h ? atomicAdd(&cursors[b_lo + i], h) : 0u;
    }

    for (int batch = 0; batch < (SC_CHUNK / BATCH); ++batch) {
        const int ebase = c0 + batch * BATCH;
        __syncthreads();                       // claim/prev-batch visible
        if (tid < nbp) bh[tid] = 0;
        __syncthreads();

        // load 8 edges/thread, compute packed entry, batch-rank via LDS atomic
        uint32_t ent[8]; uint16_t ebk[8]; uint16_t ern[8];
        #pragma unroll
        for (int i = 0; i < 8; ++i) {
            ebk[i] = 0xFFFFu;
            int e = ebase + i * SC_THREADS + tid;
            if (e < c1) {
                int c = __builtin_nontemporal_load(cls + e);
                int b = c >> BKT_SHIFT;
                if (b >= b_lo && b < b_hi) {
                    int   l = __builtin_nontemporal_load(lits + e);
                    float f = __builtin_nontemporal_load(ef + e);
                    float ev = fmaf(f, vp[l], (1.0f - f) * 0.5f);   // in [0,1]
                    ev = fminf(fmaxf(ev, 0.0f), 1.0f);
                    uint32_t evq = ev_enc(ev);
                    int ib = b - b_lo;
                    uint32_t r = atomicAdd(&bh[ib], 1u);
                    ent[i] = (evq << BKT_SHIFT) | (uint32_t)(c & (BKT_CLS - 1));
                    ebk[i] = (uint16_t)ib;
                    ern[i] = (uint16_t)r;
                }
            }
        }
        __syncthreads();

        // exclusive prefix scan of bh -> bOff (wave64 scan + wave-offset pass)
        uint32_t v = (tid < nbp) ? bh[tid] : 0u;
        uint32_t x = v;
        #pragma unroll
        for (int d = 1; d < 64; d <<= 1) {
            uint32_t n = __shfl_up(x, (unsigned)d, 64);
            if (lane >= d) x += n;
        }
        if (lane == 63) wsums[wv] = x;
        __syncthreads();
        if (wv == 0) {
            uint32_t s = (lane < 16) ? wsums[lane] : 0u;
            uint32_t y = s;
            #pragma unroll
            for (int d = 1; d < 16; d <<= 1) {
                uint32_t n = __shfl_up(y, (unsigned)d, 64);
                if (lane >= d) y += n;
            }
            if (lane < 16) wsums[lane] = y - s;   // exclusive wave offsets
        }
        __syncthreads();
        uint32_t incl = x + wsums[wv];
        if (tid < nbp) bOff[tid] = incl - v;
        if (tid == SC_THREADS - 1) totalS = incl;
        __syncthreads();

        // scatter entries into bucket-grouped LDS staging
        #pragma unroll
        for (int i = 0; i < 8; ++i) {
            if (ebk[i] != 0xFFFFu) {
                uint32_t s = bOff[ebk[i]] + ern[i];
                buf[s]  = ent[i];
                bufB[s] = ebk[i];
            }
        }
        __syncthreads();

        // coalesced write-out: consecutive threads -> consecutive positions per run
        const uint32_t tS = totalS;
        for (uint32_t s = tid; s < tS; s += SC_THREADS) {
            uint32_t ib   = bufB[s];
            uint32_t gpos = curB[ib] + (s - bOff[ib]);
            if (gpos < (uint32_t)CAP)
                payload[(size_t)ib * CAP + gpos] = buf[s];
        }
        __syncthreads();

        // advance running within-bucket offsets
        if (tid < nbp) curB[tid] += bh[tid];
    }
}

// Phase B: one block per bucket; separate nom/den LDS arrays.
__global__ __launch_bounds__(512) void
process_kernel(const uint32_t* __restrict__ payload,
               const uint32_t* __restrict__ cursors,
               const float* __restrict__ gstep,
               const float* __restrict__ epsp,
               double* __restrict__ acc,
               int b_lo) {
    __shared__ float  snom[BKT_CLS];   // 16 KB
    __shared__ float  sden[BKT_CLS];   // 16 KB
    __shared__ double wsum[8];
    const int tid = threadIdx.x;
    const int b = b_lo + blockIdx.x;

    for (int j = tid; j < BKT_CLS; j += 512) { snom[j] = 0.f; sden[j] = 0.f; }
    __syncthreads();

    const float coeff = fminf(sqrtf(gstep[0]), 10.0f);
    const uint32_t cnt = min(cursors[b], (uint32_t)CAP);
    const uint32_t* pl = payload + (size_t)blockIdx.x * CAP;

    const uint32_t nv = cnt >> 2;
    for (uint32_t k = tid; k < nv; k += 512) {
        uint4 p4 = ((const uint4*)pl)[k];
        #pragma unroll
        for (int j = 0; j < 4; ++j) {
            uint32_t p = (j == 0) ? p4.x : (j == 1) ? p4.y : (j == 2) ? p4.z : p4.w;
            int   cl = p & (BKT_CLS - 1);
            float ev = ev_dec(p >> BKT_SHIFT);
            float w  = __expf(coeff * ev);
            atomicAdd(&snom[cl], w * ev);
            atomicAdd(&sden[cl], w);
        }
    }
    for (uint32_t k = (nv << 2) + tid; k < cnt; k += 512) {
        uint32_t p = pl[k];
        int   cl = p & (BKT_CLS - 1);
        float ev = ev_dec(p >> BKT_SHIFT);
        float w  = __expf(coeff * ev);
        atomicAdd(&snom[cl], w * ev);
        atomicAdd(&sden[cl], w);
    }
    __syncthreads();

    const float eps = epsp[0];
    double local = 0.0;
    const int gbase = b << BKT_SHIFT;
    for (int j = tid; j < BKT_CLS; j += 512) {
        if (gbase + j < N_CLAUSES_C) {
            float cv = sden[j] / fmaxf(snom[j], eps);   // den / max(nom, eps)
            float t  = cv - 1.0f;
            float t2 = t * t;
            float cv2 = 1.0f + t2 * t2 * t;             // 1 + (cv-1)^5
            local += (double)logf(fmaxf(cv2, eps));
        }
    }
    #pragma unroll
    for (int off = 32; off > 0; off >>= 1) local += __shfl_down(local, off, 64);
    if ((tid & 63) == 0) wsum[tid >> 6] = local;
    __syncthreads();
    if (tid == 0) {
        double t = 0.0;
        for (int w = 0; w < 8; ++w) t += wsum[w];
        unsafeAtomicAdd(acc, t);
    }
}

__global__ void finalize_kernel(const double* __restrict__ acc,
                                const int* __restrict__ ncp,
                                float* __restrict__ out) {
    if (threadIdx.x == 0 && blockIdx.x == 0)
        out[0] = (float)(acc[0] / (double)ncp[0]);
}

extern "C" void kernel_launch(void* const* d_in, const int* in_sizes, int n_in,
                              void* d_out, int out_size, void* d_ws, size_t ws_size,
                              hipStream_t stream) {
    const float* vp    = (const float*)d_in[0];
    const int*   gmap  = (const int*)d_in[1];
    const float* ef    = (const float*)d_in[2];
    const int*   ncp   = (const int*)d_in[3];
    const float* gstep = (const float*)d_in[4];
    const float* epsp  = (const float*)d_in[5];
    float*       out   = (float*)d_out;

    const int n_edges = in_sizes[1] / 2;
    const int* lits = gmap;
    const int* cls  = gmap + n_edges;

    // choose pass count so payload fits the workspace (P=1 needs ~51MB)
    int P = 8;
    int nbp_max = (NB_TOTAL + 7) / 8;
    size_t cursors_off_w = (size_t)nbp_max * CAP;
    size_t acc_off_w = (cursors_off_w + NB_TOTAL + 1) & ~(size_t)1;
    const int cands[4] = {1, 2, 4, 8};
    for (int ci = 0; ci < 4; ++ci) {
        int cand = cands[ci];
        int nm = (NB_TOTAL + cand - 1) / cand;
        size_t pw = (size_t)nm * CAP;          // payload words
        size_t cw = pw + NB_TOTAL;             // cursors end (words)
        size_t aw = (cw + 1) & ~(size_t)1;     // 8B-aligned acc offset (words)
        size_t need = aw * 4 + 8;
        if (need <= ws_size) { P = cand; nbp_max = nm; cursors_off_w = pw; acc_off_w = aw; break; }
    }

    uint32_t* payload = (uint32_t*)d_ws;
    uint32_t* cursors = payload + cursors_off_w;
    double*   acc     = (double*)((uint32_t*)d_ws + acc_off_w);

    // zero cursors + accumulator every call (ws is poisoned, not re-zeroed)
    hipMemsetAsync(cursors, 0, (acc_off_w - cursors_off_w) * 4 + 8, stream);

    const int sc_blocks = (n_edges + SC_CHUNK - 1) / SC_CHUNK;  // 489 for 12M
    for (int p = 0; p < P; ++p) {
        int b_lo = p * nbp_max;
        int b_hi = min(NB_TOTAL, b_lo + nbp_max);
        if (b_lo >= b_hi) continue;
        scatter_kernel<<<sc_blocks, SC_THREADS, 0, stream>>>(
            vp, lits, cls, ef, payload, cursors, n_edges, b_lo, b_hi);
        process_kernel<<<b_hi - b_lo, 512, 0, stream>>>(
            payload, cursors, gstep, epsp, acc, b_lo);
    }
    finalize_kernel<<<1, 64, 0, stream>>>(acc, ncp, out);
}

// Round 7
// 275.250 us; speedup vs baseline: 1.9068x; 1.0893x over previous
//
#include <hip/hip_runtime.h>
#include <math.h>

// Problem constants: ALPHA=0.5, MAX_COEFF=10, SHARPNESS=5
// N_VARS=1e6, N_CLAUSES=4e6, N_EDGES=12e6

constexpr int   N_CLAUSES_C = 4000000;
constexpr int   BKT_SHIFT   = 12;                                        // 4096 clauses / bucket
constexpr int   BKT_CLS     = 1 << BKT_SHIFT;
constexpr int   NB_TOTAL    = (N_CLAUSES_C + BKT_CLS - 1) >> BKT_SHIFT;  // 977
constexpr int   CAP         = 13056;   // mean 12288, sd ~111; ~7 sigma, mult of 4
constexpr int   SC_THREADS  = 1024;
constexpr int   BATCH       = 8192;
constexpr int   SC_CHUNK    = 3 * BATCH;   // 24576 -> 489 blocks (~2/CU co-resident)

// ev encoding: top-20-bits-of-f32 with round-to-nearest.
// RELATIVE error <= 2^-13 at every magnitude (linear quant zeroed tiny ev and
// made cv = den/nom explode to inf). Exact for ev = k*2^-23 (jax uniform grid)
// and for 0; monotone; ev<=1.0 maps to <= 0x7F000 < 2^20.
__device__ __forceinline__ uint32_t ev_enc(float ev) {
    return (__float_as_uint(ev) + 0x400u) >> 11;
}
__device__ __forceinline__ float ev_dec(uint32_t q) {
    return __uint_as_float(q << 11);
}

// Phase A: per-batch histogram+scan -> claim per-bucket global runs -> LDS
// reorder -> coalesced payload write. No pre-pass (cls read only once).
__global__ __launch_bounds__(SC_THREADS) void
scatter_kernel(const float* __restrict__ vp,
               const int* __restrict__ lits,
               const int* __restrict__ cls,
               const float* __restrict__ ef,
               uint32_t* __restrict__ payload,   // [nbp][CAP]
               uint32_t* __restrict__ cursors,   // [NB_TOTAL], zeroed
               int n_edges, int b_lo, int b_hi) {
    __shared__ uint32_t bh[NB_TOTAL];     // per-batch histogram / counts
    __shared__ uint32_t bOff[NB_TOTAL];   // per-batch exclusive scan (LDS base)
    __shared__ uint32_t bb[NB_TOTAL];     // per-batch claimed global base
    __shared__ uint32_t buf[BATCH];       // staged packed entries (32 KB)
    __shared__ uint16_t bufB[BATCH];      // staged bucket ids (16 KB)
    __shared__ uint32_t wsums[16];
    __shared__ uint32_t totalS;

    const int tid  = threadIdx.x;
    const int lane = tid & 63;
    const int wv   = tid >> 6;
    const int nbp  = b_hi - b_lo;         // <= 977 <= SC_THREADS
    const int c0   = blockIdx.x * SC_CHUNK;
    const int c1   = min(n_edges, c0 + SC_CHUNK);

    for (int batch = 0; batch < (SC_CHUNK / BATCH); ++batch) {
        const int ebase = c0 + batch * BATCH;
        if (ebase >= c1) break;            // block-uniform: safe with barriers
        if (tid < nbp) bh[tid] = 0;
        __syncthreads();

        // load 8 edges/thread, compute packed entry, batch-rank via LDS u32 atomic
        uint32_t ent[8]; uint16_t ebk[8]; uint16_t ern[8];
        #pragma unroll
        for (int i = 0; i < 8; ++i) {
            ebk[i] = 0xFFFFu;
            int e = ebase + i * SC_THREADS + tid;
            if (e < c1) {
                int c = __builtin_nontemporal_load(cls + e);
                int b = c >> BKT_SHIFT;
                if (b >= b_lo && b < b_hi) {
                    int   l = __builtin_nontemporal_load(lits + e);
                    float f = __builtin_nontemporal_load(ef + e);
                    float ev = fmaf(f, vp[l], (1.0f - f) * 0.5f);   // in [0,1]
                    ev = fminf(fmaxf(ev, 0.0f), 1.0f);
                    uint32_t evq = ev_enc(ev);
                    int ib = b - b_lo;
                    uint32_t r = atomicAdd(&bh[ib], 1u);
                    ent[i] = (evq << BKT_SHIFT) | (uint32_t)(c & (BKT_CLS - 1));
                    ebk[i] = (uint16_t)ib;
                    ern[i] = (uint16_t)r;
                }
            }
        }
        __syncthreads();

        // exclusive prefix scan of bh -> bOff; claim global runs -> bb
        uint32_t v = (tid < nbp) ? bh[tid] : 0u;
        uint32_t x = v;
        #pragma unroll
        for (int d = 1; d < 64; d <<= 1) {
            uint32_t n = __shfl_up(x, (unsigned)d, 64);
            if (lane >= d) x += n;
        }
        if (lane == 63) wsums[wv] = x;
        __syncthreads();
        if (wv == 0) {
            uint32_t s = (lane < 16) ? wsums[lane] : 0u;
            uint32_t y = s;
            #pragma unroll
            for (int d = 1; d < 16; d <<= 1) {
                uint32_t n = __shfl_up(y, (unsigned)d, 64);
                if (lane >= d) y += n;
            }
            if (lane < 16) wsums[lane] = y - s;   // exclusive wave offsets
        }
        __syncthreads();
        uint32_t incl = x + wsums[wv];
        if (tid < nbp) {
            bOff[tid] = incl - v;
            bb[tid]   = v ? atomicAdd(&cursors[b_lo + tid], v) : 0u;
        }
        if (tid == SC_THREADS - 1) totalS = incl;
        __syncthreads();

        // scatter entries into bucket-grouped LDS staging
        #pragma unroll
        for (int i = 0; i < 8; ++i) {
            if (ebk[i] != 0xFFFFu) {
                uint32_t s = bOff[ebk[i]] + ern[i];
                buf[s]  = ent[i];
                bufB[s] = ebk[i];
            }
        }
        __syncthreads();

        // coalesced write-out: consecutive threads -> consecutive run positions
        const uint32_t tS = totalS;
        for (uint32_t s = tid; s < tS; s += SC_THREADS) {
            uint32_t ib   = bufB[s];
            uint32_t gpos = bb[ib] + (s - bOff[ib]);
            if (gpos < (uint32_t)CAP)
                payload[(size_t)ib * CAP + gpos] = buf[s];
        }
        __syncthreads();   // protect bh re-zero next batch
    }
}

// Phase B: one block per bucket; native ds_add_f32 via unsafeAtomicAdd.
__global__ __launch_bounds__(512) void
process_kernel(const uint32_t* __restrict__ payload,
               const uint32_t* __restrict__ cursors,
               const float* __restrict__ gstep,
               const float* __restrict__ epsp,
               double* __restrict__ acc,
               int b_lo) {
    __shared__ float  snom[BKT_CLS];   // 16 KB
    __shared__ float  sden[BKT_CLS];   // 16 KB
    __shared__ double wsum[8];
    const int tid = threadIdx.x;
    const int b = b_lo + blockIdx.x;

    for (int j = tid; j < BKT_CLS; j += 512) { snom[j] = 0.f; sden[j] = 0.f; }
    __syncthreads();

    const float coeff = fminf(sqrtf(gstep[0]), 10.0f);
    const uint32_t cnt = min(cursors[b], (uint32_t)CAP);
    const uint32_t* pl = payload + (size_t)blockIdx.x * CAP;

    const uint32_t nv = cnt >> 2;
    for (uint32_t k = tid; k < nv; k += 512) {
        uint4 p4 = ((const uint4*)pl)[k];
        #pragma unroll
        for (int j = 0; j < 4; ++j) {
            uint32_t p = (j == 0) ? p4.x : (j == 1) ? p4.y : (j == 2) ? p4.z : p4.w;
            int   cl = p & (BKT_CLS - 1);
            float ev = ev_dec(p >> BKT_SHIFT);
            float w  = __expf(coeff * ev);
            unsafeAtomicAdd(&snom[cl], w * ev);   // ds_add_f32 (no CAS loop)
            unsafeAtomicAdd(&sden[cl], w);
        }
    }
    for (uint32_t k = (nv << 2) + tid; k < cnt; k += 512) {
        uint32_t p = pl[k];
        int   cl = p & (BKT_CLS - 1);
        float ev = ev_dec(p >> BKT_SHIFT);
        float w  = __expf(coeff * ev);
        unsafeAtomicAdd(&snom[cl], w * ev);
        unsafeAtomicAdd(&sden[cl], w);
    }
    __syncthreads();

    const float eps = epsp[0];
    double local = 0.0;
    const int gbase = b << BKT_SHIFT;
    for (int j = tid; j < BKT_CLS; j += 512) {
        if (gbase + j < N_CLAUSES_C) {
            float cv = sden[j] / fmaxf(snom[j], eps);   // den / max(nom, eps)
            float t  = cv - 1.0f;
            float t2 = t * t;
            float cv2 = 1.0f + t2 * t2 * t;             // 1 + (cv-1)^5
            local += (double)__logf(fmaxf(cv2, eps));
        }
    }
    #pragma unroll
    for (int off = 32; off > 0; off >>= 1) local += __shfl_down(local, off, 64);
    if ((tid & 63) == 0) wsum[tid >> 6] = local;
    __syncthreads();
    if (tid == 0) {
        double t = 0.0;
        for (int w = 0; w < 8; ++w) t += wsum[w];
        unsafeAtomicAdd(acc, t);
    }
}

__global__ void finalize_kernel(const double* __restrict__ acc,
                                const int* __restrict__ ncp,
                                float* __restrict__ out) {
    if (threadIdx.x == 0 && blockIdx.x == 0)
        out[0] = (float)(acc[0] / (double)ncp[0]);
}

extern "C" void kernel_launch(void* const* d_in, const int* in_sizes, int n_in,
                              void* d_out, int out_size, void* d_ws, size_t ws_size,
                              hipStream_t stream) {
    const float* vp    = (const float*)d_in[0];
    const int*   gmap  = (const int*)d_in[1];
    const float* ef    = (const float*)d_in[2];
    const int*   ncp   = (const int*)d_in[3];
    const float* gstep = (const float*)d_in[4];
    const float* epsp  = (const float*)d_in[5];
    float*       out   = (float*)d_out;

    const int n_edges = in_sizes[1] / 2;
    const int* lits = gmap;
    const int* cls  = gmap + n_edges;

    // choose pass count so payload fits the workspace (P=1 needs ~51MB)
    int P = 8;
    int nbp_max = (NB_TOTAL + 7) / 8;
    size_t cursors_off_w = (size_t)nbp_max * CAP;
    size_t acc_off_w = (cursors_off_w + NB_TOTAL + 1) & ~(size_t)1;
    const int cands[4] = {1, 2, 4, 8};
    for (int ci = 0; ci < 4; ++ci) {
        int cand = cands[ci];
        int nm = (NB_TOTAL + cand - 1) / cand;
        size_t pw = (size_t)nm * CAP;          // payload words
        size_t cw = pw + NB_TOTAL;             // cursors end (words)
        size_t aw = (cw + 1) & ~(size_t)1;     // 8B-aligned acc offset (words)
        size_t need = aw * 4 + 8;
        if (need <= ws_size) { P = cand; nbp_max = nm; cursors_off_w = pw; acc_off_w = aw; break; }
    }

    uint32_t* payload = (uint32_t*)d_ws;
    uint32_t* cursors = payload + cursors_off_w;
    double*   acc     = (double*)((uint32_t*)d_ws + acc_off_w);

    // zero cursors + accumulator every call (ws is poisoned, not re-zeroed)
    hipMemsetAsync(cursors, 0, (acc_off_w - cursors_off_w) * 4 + 8, stream);

    const int sc_blocks = (n_edges + SC_CHUNK - 1) / SC_CHUNK;  // 489 for 12M
    for (int p = 0; p < P; ++p) {
        int b_lo = p * nbp_max;
        int b_hi = min(NB_TOTAL, b_lo + nbp_max);
        if (b_lo >= b_hi) continue;
        scatter_kernel<<<sc_blocks, SC_THREADS, 0, stream>>>(
            vp, lits, cls, ef, payload, cursors, n_edges, b_lo, b_hi);
        process_kernel<<<b_hi - b_lo, 512, 0, stream>>>(
            payload, cursors, gstep, epsp, acc, b_lo);
    }
    finalize_kernel<<<1, 64, 0, stream>>>(acc, ncp, out);
}

// Round 8
// 181.175 us; speedup vs baseline: 2.8969x; 1.5192x over previous
//
#include <hip/hip_runtime.h>
#include <math.h>

// Problem constants: ALPHA=0.5, MAX_COEFF=10, SHARPNESS=5
// N_VARS=1e6, N_CLAUSES=4e6, N_EDGES=12e6

constexpr int   N_CLAUSES_C = 4000000;
constexpr int   BKT_SHIFT   = 12;                                        // 4096 clauses / bucket
constexpr int   BKT_CLS     = 1 << BKT_SHIFT;
constexpr int   NB_TOTAL    = (N_CLAUSES_C + BKT_CLS - 1) >> BKT_SHIFT;  // 977
constexpr int   CAP         = 13056;   // mean 12288, sd ~111; ~7 sigma, mult of 4
constexpr int   SC_THREADS  = 1024;
constexpr int   BATCH       = 8192;
constexpr int   SC_CHUNK    = 3 * BATCH;   // 24576 -> 489 blocks
constexpr int   PR_THREADS  = 512;

// ev encoding: top-20-bits-of-f32, round-to-nearest. RELATIVE err <= 2^-13 at
// every magnitude (linear quant zeroed tiny ev -> cv=den/nom exploded to inf).
// Exact for 0 and monotone; ev<=1.0 -> 0x7F000 < 2^20.
__device__ __forceinline__ uint32_t ev_enc(float ev) {
    return (__float_as_uint(ev) + 0x400u) >> 11;
}
__device__ __forceinline__ float ev_dec(uint32_t q) {
    return __uint_as_float(q << 11);
}

// Phase A: per-batch histogram+scan -> claim per-bucket global runs -> LDS
// reorder -> coalesced payload write. (unchanged from R7: 139us, WRITE 88MB)
__global__ __launch_bounds__(SC_THREADS) void
scatter_kernel(const float* __restrict__ vp,
               const int* __restrict__ lits,
               const int* __restrict__ cls,
               const float* __restrict__ ef,
               uint32_t* __restrict__ payload,   // [nbp][CAP]
               uint32_t* __restrict__ cursors,   // [NB_TOTAL], zeroed
               int n_edges, int b_lo, int b_hi) {
    __shared__ uint32_t bh[NB_TOTAL];     // per-batch histogram / counts
    __shared__ uint32_t bOff[NB_TOTAL];   // per-batch exclusive scan (LDS base)
    __shared__ uint32_t bb[NB_TOTAL];     // per-batch claimed global base
    __shared__ uint32_t buf[BATCH];       // staged packed entries (32 KB)
    __shared__ uint16_t bufB[BATCH];      // staged bucket ids (16 KB)
    __shared__ uint32_t wsums[16];
    __shared__ uint32_t totalS;

    const int tid  = threadIdx.x;
    const int lane = tid & 63;
    const int wv   = tid >> 6;
    const int nbp  = b_hi - b_lo;         // <= 977 <= SC_THREADS
    const int c0   = blockIdx.x * SC_CHUNK;
    const int c1   = min(n_edges, c0 + SC_CHUNK);

    for (int batch = 0; batch < (SC_CHUNK / BATCH); ++batch) {
        const int ebase = c0 + batch * BATCH;
        if (ebase >= c1) break;            // block-uniform
        if (tid < nbp) bh[tid] = 0;
        __syncthreads();

        uint32_t ent[8]; uint16_t ebk[8]; uint16_t ern[8];
        #pragma unroll
        for (int i = 0; i < 8; ++i) {
            ebk[i] = 0xFFFFu;
            int e = ebase + i * SC_THREADS + tid;
            if (e < c1) {
                int c = __builtin_nontemporal_load(cls + e);
                int b = c >> BKT_SHIFT;
                if (b >= b_lo && b < b_hi) {
                    int   l = __builtin_nontemporal_load(lits + e);
                    float f = __builtin_nontemporal_load(ef + e);
                    float ev = fmaf(f, vp[l], (1.0f - f) * 0.5f);   // in [0,1]
                    ev = fminf(fmaxf(ev, 0.0f), 1.0f);
                    uint32_t evq = ev_enc(ev);
                    int ib = b - b_lo;
                    uint32_t r = atomicAdd(&bh[ib], 1u);
                    ent[i] = (evq << BKT_SHIFT) | (uint32_t)(c & (BKT_CLS - 1));
                    ebk[i] = (uint16_t)ib;
                    ern[i] = (uint16_t)r;
                }
            }
        }
        __syncthreads();

        // exclusive prefix scan of bh -> bOff; claim global runs -> bb
        uint32_t v = (tid < nbp) ? bh[tid] : 0u;
        uint32_t x = v;
        #pragma unroll
        for (int d = 1; d < 64; d <<= 1) {
            uint32_t n = __shfl_up(x, (unsigned)d, 64);
            if (lane >= d) x += n;
        }
        if (lane == 63) wsums[wv] = x;
        __syncthreads();
        if (wv == 0) {
            uint32_t s = (lane < 16) ? wsums[lane] : 0u;
            uint32_t y = s;
            #pragma unroll
            for (int d = 1; d < 16; d <<= 1) {
                uint32_t n = __shfl_up(y, (unsigned)d, 64);
                if (lane >= d) y += n;
            }
            if (lane < 16) wsums[lane] = y - s;
        }
        __syncthreads();
        uint32_t incl = x + wsums[wv];
        if (tid < nbp) {
            bOff[tid] = incl - v;
            bb[tid]   = v ? atomicAdd(&cursors[b_lo + tid], v) : 0u;
        }
        if (tid == SC_THREADS - 1) totalS = incl;
        __syncthreads();

        #pragma unroll
        for (int i = 0; i < 8; ++i) {
            if (ebk[i] != 0xFFFFu) {
                uint32_t s = bOff[ebk[i]] + ern[i];
                buf[s]  = ent[i];
                bufB[s] = ebk[i];
            }
        }
        __syncthreads();

        const uint32_t tS = totalS;
        for (uint32_t s = tid; s < tS; s += SC_THREADS) {
            uint32_t ib   = bufB[s];
            uint32_t gpos = bb[ib] + (s - bOff[ib]);
            if (gpos < (uint32_t)CAP)
                payload[(size_t)ib * CAP + gpos] = buf[s];
        }
        __syncthreads();
    }
}

// Phase B: one block per bucket. Counting-sort by clause (u32 LDS atomics
// ONLY), then per-thread register accumulation — no fp atomics anywhere.
// LDS: offp (u16-packed counters/offsets, 8KB) + srt (sorted entries, 52KB).
__global__ __launch_bounds__(PR_THREADS) void
process_kernel(const uint32_t* __restrict__ payload,
               const uint32_t* __restrict__ cursors,
               const float* __restrict__ gstep,
               const float* __restrict__ epsp,
               double* __restrict__ acc,
               int b_lo) {
    __shared__ uint32_t offp[BKT_CLS / 2];   // 2 u16 counts per word, 8 KB
    __shared__ uint32_t srt[CAP];            // 52.2 KB
    __shared__ uint32_t wscan[8];
    __shared__ double   wsum[8];
    const int tid  = threadIdx.x;
    const int lane = tid & 63;
    const int wv   = tid >> 6;
    const int b    = b_lo + blockIdx.x;

    for (int j = tid; j < BKT_CLS / 2; j += PR_THREADS) offp[j] = 0;
    __syncthreads();

    const uint32_t cnt = min(cursors[b], (uint32_t)CAP);
    const uint32_t* pl = payload + (size_t)blockIdx.x * CAP;
    const uint32_t nv = cnt >> 2;

    // pass 1: clause histogram (packed u16 halves; counts < 2^16, no carry)
    for (uint32_t k = tid; k < nv; k += PR_THREADS) {
        uint4 p4 = ((const uint4*)pl)[k];
        uint32_t c;
        c = p4.x & (BKT_CLS - 1); atomicAdd(&offp[c >> 1], 1u << ((c & 1) << 4));
        c = p4.y & (BKT_CLS - 1); atomicAdd(&offp[c >> 1], 1u << ((c & 1) << 4));
        c = p4.z & (BKT_CLS - 1); atomicAdd(&offp[c >> 1], 1u << ((c & 1) << 4));
        c = p4.w & (BKT_CLS - 1); atomicAdd(&offp[c >> 1], 1u << ((c & 1) << 4));
    }
    for (uint32_t k = (nv << 2) + tid; k < cnt; k += PR_THREADS) {
        uint32_t c = pl[k] & (BKT_CLS - 1);
        atomicAdd(&offp[c >> 1], 1u << ((c & 1) << 4));
    }
    __syncthreads();

    // in-place exclusive scan of 4096 packed-u16 counts (thread owns 4 words)
    uint32_t pk[4];
    const int jb = tid * 4;
    uint32_t t = 0;
    #pragma unroll
    for (int i = 0; i < 4; ++i) {
        pk[i] = offp[jb + i];
        t += (pk[i] & 0xFFFFu) + (pk[i] >> 16);
    }
    uint32_t x = t;
    #pragma unroll
    for (int d = 1; d < 64; d <<= 1) {
        uint32_t n = __shfl_up(x, (unsigned)d, 64);
        if (lane >= d) x += n;
    }
    if (lane == 63) wscan[wv] = x;
    __syncthreads();
    if (tid == 0) {
        uint32_t r = 0;
        #pragma unroll
        for (int w = 0; w < 8; ++w) { uint32_t tm = wscan[w]; wscan[w] = r; r += tm; }
    }
    __syncthreads();
    uint32_t run = (x - t) + wscan[wv];
    #pragma unroll
    for (int i = 0; i < 4; ++i) {
        uint32_t lo = pk[i] & 0xFFFFu, hi = pk[i] >> 16;
        offp[jb + i] = run | ((run + lo) << 16);   // both starts <= cnt < 2^16
        run += lo + hi;
    }
    __syncthreads();

    // pass 2: place entries clause-sorted (ds_add_rtn_u32 rank)
    for (uint32_t k = tid; k < nv; k += PR_THREADS) {
        uint4 p4 = ((const uint4*)pl)[k];
        #pragma unroll
        for (int j = 0; j < 4; ++j) {
            uint32_t p = (j == 0) ? p4.x : (j == 1) ? p4.y : (j == 2) ? p4.z : p4.w;
            uint32_t c = p & (BKT_CLS - 1);
            uint32_t sh = (c & 1) << 4;
            uint32_t r = atomicAdd(&offp[c >> 1], 1u << sh);
            srt[(r >> sh) & 0xFFFFu] = p;
        }
    }
    for (uint32_t k = (nv << 2) + tid; k < cnt; k += PR_THREADS) {
        uint32_t p = pl[k];
        uint32_t c = p & (BKT_CLS - 1);
        uint32_t sh = (c & 1) << 4;
        uint32_t r = atomicAdd(&offp[c >> 1], 1u << sh);
        srt[(r >> sh) & 0xFFFFu] = p;
    }
    __syncthreads();
    // now offp half j == END of segment j; start(j) = end(j-1), start(0)=0

    // pass 3: per-clause register accumulation + log epilogue
    const float coeff = fminf(sqrtf(gstep[0]), 10.0f);
    const float eps   = epsp[0];
    const int gbase = b << BKT_SHIFT;
    double local = 0.0;
    for (int j = tid; j < BKT_CLS; j += PR_THREADS) {
        if (gbase + j < N_CLAUSES_C) {
            uint32_t e = (offp[j >> 1] >> ((j & 1) << 4)) & 0xFFFFu;
            uint32_t s = 0;
            if (j > 0) {
                int jm = j - 1;
                s = (offp[jm >> 1] >> ((jm & 1) << 4)) & 0xFFFFu;
            }
            float nom = 0.f, den = 0.f;
            for (uint32_t k = s; k < e; ++k) {
                float ev = ev_dec(srt[k] >> BKT_SHIFT);
                float w  = __expf(coeff * ev);
                nom = fmaf(w, ev, nom);
                den += w;
            }
            float cv = den / fmaxf(nom, eps);   // empty clause: 0/eps = 0 (ref-match)
            float tt = cv - 1.0f;
            float t2 = tt * tt;
            float cv2 = 1.0f + t2 * t2 * tt;    // 1 + (cv-1)^5
            local += (double)__logf(fmaxf(cv2, eps));
        }
    }
    #pragma unroll
    for (int off = 32; off > 0; off >>= 1) local += __shfl_down(local, off, 64);
    if (lane == 0) wsum[wv] = local;
    __syncthreads();
    if (tid == 0) {
        double s = 0.0;
        #pragma unroll
        for (int w = 0; w < 8; ++w) s += wsum[w];
        unsafeAtomicAdd(acc, s);
    }
}

__global__ void finalize_kernel(const double* __restrict__ acc,
                                const int* __restrict__ ncp,
                                float* __restrict__ out) {
    if (threadIdx.x == 0 && blockIdx.x == 0)
        out[0] = (float)(acc[0] / (double)ncp[0]);
}

extern "C" void kernel_launch(void* const* d_in, const int* in_sizes, int n_in,
                              void* d_out, int out_size, void* d_ws, size_t ws_size,
                              hipStream_t stream) {
    const float* vp    = (const float*)d_in[0];
    const int*   gmap  = (const int*)d_in[1];
    const float* ef    = (const float*)d_in[2];
    const int*   ncp   = (const int*)d_in[3];
    const float* gstep = (const float*)d_in[4];
    const float* epsp  = (const float*)d_in[5];
    float*       out   = (float*)d_out;

    const int n_edges = in_sizes[1] / 2;
    const int* lits = gmap;
    const int* cls  = gmap + n_edges;

    // choose pass count so payload fits the workspace (P=1 needs ~51MB)
    int P = 8;
    int nbp_max = (NB_TOTAL + 7) / 8;
    size_t cursors_off_w = (size_t)nbp_max * CAP;
    size_t acc_off_w = (cursors_off_w + NB_TOTAL + 1) & ~(size_t)1;
    const int cands[4] = {1, 2, 4, 8};
    for (int ci = 0; ci < 4; ++ci) {
        int cand = cands[ci];
        int nm = (NB_TOTAL + cand - 1) / cand;
        size_t pw = (size_t)nm * CAP;
        size_t cw = pw + NB_TOTAL;
        size_t aw = (cw + 1) & ~(size_t)1;
        size_t need = aw * 4 + 8;
        if (need <= ws_size) { P = cand; nbp_max = nm; cursors_off_w = pw; acc_off_w = aw; break; }
    }

    uint32_t* payload = (uint32_t*)d_ws;
    uint32_t* cursors = payload + cursors_off_w;
    double*   acc     = (double*)((uint32_t*)d_ws + acc_off_w);

    // zero cursors + accumulator every call (ws is poisoned, not re-zeroed)
    hipMemsetAsync(cursors, 0, (acc_off_w - cursors_off_w) * 4 + 8, stream);

    const int sc_blocks = (n_edges + SC_CHUNK - 1) / SC_CHUNK;  // 489 for 12M
    for (int p = 0; p < P; ++p) {
        int b_lo = p * nbp_max;
        int b_hi = min(NB_TOTAL, b_lo + nbp_max);
        if (b_lo >= b_hi) continue;
        scatter_kernel<<<sc_blocks, SC_THREADS, 0, stream>>>(
            vp, lits, cls, ef, payload, cursors, n_edges, b_lo, b_hi);
        process_kernel<<<b_hi - b_lo, PR_THREADS, 0, stream>>>(
            payload, cursors, gstep, epsp, acc, b_lo);
    }
    finalize_kernel<<<1, 64, 0, stream>>>(acc, ncp, out);
}